// Round 1
// baseline (1647.576 us; speedup 1.0000x reference)
//
#include <hip/hip_runtime.h>
#include <math.h>

// ---------------------------------------------------------------------------
// EdgeClassifier: 2x SAGEConv(mean) -> per-node MLP -> edge scorer
// Key restructurings:
//  * relu(h[src]@Wnp+b) == relu(h@Wnp+b)[src]  -> per-node, not per-edge
//  * ef@W splits into per-node S/T tables + tiny edge_feat term
//  * efw@Wl1 == w * (ef@Wl1)  (w is a per-edge scalar)
//  * SAGE aggregation: project-then-scatter with f32 atomics, 1 wave/edge
// ---------------------------------------------------------------------------

__global__ void zero_k(float* __restrict__ p, int n) {
    int i = blockIdx.x * blockDim.x + threadIdx.x;
    if (i < n) p[i] = 0.0f;
}

__global__ void count_deg(const int* __restrict__ dst, float* __restrict__ deg, int E) {
    int i = blockIdx.x * blockDim.x + threadIdx.x;
    if (i < E) unsafeAtomicAdd(&deg[dst[i]], 1.0f);
}

__global__ void inv_deg_k(float* __restrict__ deg, int N) {
    int i = blockIdx.x * blockDim.x + threadIdx.x;
    if (i < N) deg[i] = 1.0f / fmaxf(deg[i], 1.0f);
}

// p[n][j] = sum_{k<4} nf[n][k] * W[k][j]
__global__ void proj1_k(const float* __restrict__ nf, const float* __restrict__ W,
                        float* __restrict__ p, int N) {
    int t = blockIdx.x * blockDim.x + threadIdx.x;
    if (t >= N * 64) return;
    int n = t >> 6, j = t & 63;
    const float* r = nf + n * 4;
    p[t] = r[0] * W[j] + r[1] * W[64 + j] + r[2] * W[128 + j] + r[3] * W[192 + j];
}

// h[n][j] = relu(sum_{k<4} nf[n][k]*Ws[k][j] + agg[n][j]*inv[n] + b[j])
__global__ void sage1_fin(const float* __restrict__ nf, const float* __restrict__ Ws,
                          const float* __restrict__ b, const float* __restrict__ agg,
                          const float* __restrict__ inv, float* __restrict__ h, int N) {
    int t = blockIdx.x * blockDim.x + threadIdx.x;
    if (t >= N * 64) return;
    int n = t >> 6, j = t & 63;
    const float* r = nf + n * 4;
    float v = b[j] + agg[t] * inv[n]
            + r[0] * Ws[j] + r[1] * Ws[64 + j] + r[2] * Ws[128 + j] + r[3] * Ws[192 + j];
    h[t] = fmaxf(v, 0.0f);
}

// one wave per edge: lane j scatters feature j
__global__ void scatter_k(const int* __restrict__ src, const int* __restrict__ dst,
                          const float* __restrict__ p, float* __restrict__ agg, int E) {
    int t = blockIdx.x * blockDim.x + threadIdx.x;
    int e = t >> 6;
    if (e >= E) return;
    int j = t & 63;
    unsafeAtomicAdd(&agg[dst[e] * 64 + j], p[src[e] * 64 + j]);
}

// out[n][j] = act( sum_{k<64} h[n][k]*W[k][j] [+ b[j]] [+ agg[n][j]*inv[n]] )
template <bool RELU, bool AGG, bool HASB>
__global__ void mm64_k(const float* __restrict__ h, const float* __restrict__ W,
                       const float* __restrict__ b, const float* __restrict__ agg,
                       const float* __restrict__ inv, float* __restrict__ out, int N) {
    __shared__ float lh[256];   // 4 node rows
    int t = blockIdx.x * 256 + threadIdx.x;
    int gidx = blockIdx.x * 256 + threadIdx.x;  // same flat layout
    lh[threadIdx.x] = (gidx < N * 64) ? h[gidx] : 0.0f;
    __syncthreads();
    if (t >= N * 64) return;
    int n = t >> 6, j = t & 63;
    const float* lr = lh + ((threadIdx.x >> 6) << 6);
    float acc = HASB ? b[j] : 0.0f;
#pragma unroll
    for (int k = 0; k < 64; k++) acc += lr[k] * W[k * 64 + j];
    if (AGG) acc += agg[t] * inv[n];
    out[t] = RELU ? fmaxf(acc, 0.0f) : acc;
}

// S[n][c] (c<64: hn@We1 rows 0..63 ; c>=64: hn@Wl1 rows 0..63)
// T[n][c] (c<64: hn@We1 rows 64..127; c>=64: hn@Wl1 rows 64..127)
__global__ void st_k(const float* __restrict__ hn, const float* __restrict__ We1,
                     const float* __restrict__ Wl1, float* __restrict__ S,
                     float* __restrict__ T, int N) {
    __shared__ float lh[128];   // 2 node rows
    int t = blockIdx.x * 256 + threadIdx.x;
    if (threadIdx.x < 128) {
        int gidx = blockIdx.x * 128 + threadIdx.x;
        lh[threadIdx.x] = (gidx < N * 64) ? hn[gidx] : 0.0f;
    }
    __syncthreads();
    if (t >= N * 128) return;
    int n = t >> 7, c = t & 127;
    int j = c & 63;
    const float* WA = (c < 64) ? We1 : Wl1;
    const float* lr = lh + ((threadIdx.x >> 7) << 6);
    float aS = 0.0f, aT = 0.0f;
#pragma unroll
    for (int k = 0; k < 64; k++) {
        float v = lr[k];
        aS += v * WA[k * 64 + j];          // rows 0..63
        aT += v * WA[(64 + k) * 64 + j];   // rows 64..127
    }
    S[n * 128 + c] = aS;
    T[n * 128 + c] = aT;
}

// one wave per edge
__global__ void edge_k(const int* __restrict__ src, const int* __restrict__ dst,
                       const float* __restrict__ ef,
                       const float* __restrict__ S, const float* __restrict__ T,
                       const float* __restrict__ We1, const float* __restrict__ be1,
                       const float* __restrict__ We2, const float* __restrict__ be2,
                       const float* __restrict__ Wl1, const float* __restrict__ bl1,
                       const float* __restrict__ Wl2, const float* __restrict__ bl2,
                       float* __restrict__ out, int E) {
    int t = blockIdx.x * 256 + threadIdx.x;
    int e = t >> 6;
    if (e >= E) return;
    int j = t & 63;
    int s = src[e], d = dst[e];
    float t1 = S[s * 128 + j] + T[d * 128 + j] + be1[j];          // (ef@We1)_j + be1
    float u  = S[s * 128 + 64 + j] + T[d * 128 + 64 + j];         // (ef@Wl1)_j (no bias yet)
#pragma unroll
    for (int k = 0; k < 5; k++) {
        float ek = ef[e * 5 + k];
        t1 += ek * We1[(128 + k) * 64 + j];
        u  += ek * Wl1[(128 + k) * 64 + j];
    }
    float z = tanhf(t1) * We2[j];
#pragma unroll
    for (int m = 32; m > 0; m >>= 1) z += __shfl_xor(z, m);
    float w = 1.0f / (1.0f + expf(-(z + be2[0])));
    float o = fmaxf(w * u + bl1[j], 0.0f) * Wl2[j];
#pragma unroll
    for (int m = 32; m > 0; m >>= 1) o += __shfl_xor(o, m);
    if (j == 0) out[e] = o + bl2[0];
}

extern "C" void kernel_launch(void* const* d_in, const int* in_sizes, int n_in,
                              void* d_out, int out_size, void* d_ws, size_t ws_size,
                              hipStream_t stream) {
    const float* nf  = (const float*)d_in[0];
    const float* ef  = (const float*)d_in[1];
    const int*   src = (const int*)d_in[2];
    const int*   dst = (const int*)d_in[3];
    const float* W1s = (const float*)d_in[4];
    const float* W1n = (const float*)d_in[5];
    const float* b1  = (const float*)d_in[6];
    const float* W2s = (const float*)d_in[7];
    const float* W2n = (const float*)d_in[8];
    const float* b2  = (const float*)d_in[9];
    const float* Wnp = (const float*)d_in[10];
    const float* bnp = (const float*)d_in[11];
    const float* We1 = (const float*)d_in[12];
    const float* be1 = (const float*)d_in[13];
    const float* We2 = (const float*)d_in[14];
    const float* be2 = (const float*)d_in[15];
    const float* Wl1 = (const float*)d_in[16];
    const float* bl1 = (const float*)d_in[17];
    const float* Wl2 = (const float*)d_in[18];
    const float* bl2 = (const float*)d_in[19];

    const int N = in_sizes[0] / 4;
    const int E = in_sizes[2];

    // workspace layout (floats): inv(N) | G(64N) | X(64N) | Z(64N) | T(128N)
    // S overlays [X,Z] (128N, contiguous). Peak use = 321N floats ~= 128.4 MB.
    float* wsf = (float*)d_ws;
    float* inv = wsf;                         // N
    float* G   = wsf + N;                     // 64N: agg1, agg2, then hn
    float* X   = G + (size_t)64 * N;          // 64N: p1, p2, then h2; start of S
    float* Z   = X + (size_t)64 * N;          // 64N: h1
    float* S   = X;                           // 128N overlaying X..Z
    float* T   = Z + (size_t)64 * N;          // 128N
    float* out = (float*)d_out;

    const int NT = N * 64;                    // 6.4M
    const int nblkN  = (NT + 255) / 256;
    const int nblkN2 = (N * 128 + 255) / 256;
    const int nblkE  = (E + 255) / 256;
    const int nblkEw = (int)(((long long)E * 64 + 255) / 256);

    // degree -> inv_deg
    zero_k<<<(N + 255) / 256, 256, 0, stream>>>(inv, N);
    count_deg<<<nblkE, 256, 0, stream>>>(dst, inv, E);
    inv_deg_k<<<(N + 255) / 256, 256, 0, stream>>>(inv, N);

    // layer 1
    proj1_k<<<nblkN, 256, 0, stream>>>(nf, W1n, X, N);
    zero_k<<<nblkN, 256, 0, stream>>>(G, NT);
    scatter_k<<<nblkEw, 256, 0, stream>>>(src, dst, X, G, E);
    sage1_fin<<<nblkN, 256, 0, stream>>>(nf, W1s, b1, G, inv, Z, N);    // h1 -> Z

    // layer 2
    mm64_k<false, false, false><<<nblkN, 256, 0, stream>>>(Z, W2n, nullptr, nullptr, nullptr, X, N); // p2 -> X
    zero_k<<<nblkN, 256, 0, stream>>>(G, NT);
    scatter_k<<<nblkEw, 256, 0, stream>>>(src, dst, X, G, E);
    mm64_k<true, true, true><<<nblkN, 256, 0, stream>>>(Z, W2s, b2, G, inv, X, N);  // h2 -> X

    // per-node MLP + S/T tables
    mm64_k<true, false, true><<<nblkN, 256, 0, stream>>>(X, Wnp, bnp, nullptr, nullptr, G, N); // hn -> G
    st_k<<<nblkN2, 256, 0, stream>>>(G, We1, Wl1, S, T, N);

    // per-edge scoring
    edge_k<<<nblkEw, 256, 0, stream>>>(src, dst, ef, S, T,
                                       We1, be1, We2, be2, Wl1, bl1, Wl2, bl2,
                                       out, E);
}

// Round 2
// 1348.244 us; speedup vs baseline: 1.2220x; 1.2220x over previous
//
#include <hip/hip_runtime.h>
#include <math.h>

// ---------------------------------------------------------------------------
// EdgeClassifier: 2x SAGEConv(mean) -> per-node MLP -> edge scorer
//  * per-node algebra: relu(h[src]@W+b) == relu(h@W+b)[src]
//  * ef@W splits into per-node ST table (N x 256) + tiny edge_feat tail
//  * edge_k: persistent waves, weights in registers, fast tanh/sigmoid
//  * node matmuls: register-blocked 64x64-tile GEMM (4x4 per thread)
// ---------------------------------------------------------------------------

__device__ __forceinline__ float fast_tanh(float x) {
    x = fminf(fmaxf(x, -15.f), 15.f);
    float e2 = __expf(2.f * x);
    return (e2 - 1.f) * __builtin_amdgcn_rcpf(e2 + 1.f);
}
__device__ __forceinline__ float fast_sigmoid(float x) {
    x = fminf(fmaxf(x, -60.f), 60.f);
    return __builtin_amdgcn_rcpf(1.f + __expf(-x));
}

__global__ void zero_k(float* __restrict__ p, int n) {
    int i = blockIdx.x * blockDim.x + threadIdx.x;
    if (i < n) p[i] = 0.0f;
}

__global__ void count_deg(const int* __restrict__ dst, float* __restrict__ deg, int E) {
    int i = blockIdx.x * blockDim.x + threadIdx.x;
    if (i < E) unsafeAtomicAdd(&deg[dst[i]], 1.0f);
}

__global__ void inv_deg_k(float* __restrict__ deg, int N) {
    int i = blockIdx.x * blockDim.x + threadIdx.x;
    if (i < N) deg[i] = 1.0f / fmaxf(deg[i], 1.0f);
}

// p[n][j] = sum_{k<4} nf[n][k] * W[k][j]
__global__ void proj1_k(const float* __restrict__ nf, const float* __restrict__ W,
                        float* __restrict__ p, int N) {
    int t = blockIdx.x * blockDim.x + threadIdx.x;
    if (t >= N * 64) return;
    int n = t >> 6, j = t & 63;
    float4 r = ((const float4*)nf)[n];
    p[t] = r.x * W[j] + r.y * W[64 + j] + r.z * W[128 + j] + r.w * W[192 + j];
}

// h[n][j] = relu(sum_{k<4} nf[n][k]*Ws[k][j] + agg[n][j]*inv[n] + b[j])
__global__ void sage1_fin(const float* __restrict__ nf, const float* __restrict__ Ws,
                          const float* __restrict__ b, const float* __restrict__ agg,
                          const float* __restrict__ inv, float* __restrict__ h, int N) {
    int t = blockIdx.x * blockDim.x + threadIdx.x;
    if (t >= N * 64) return;
    int n = t >> 6, j = t & 63;
    float4 r = ((const float4*)nf)[n];
    float v = b[j] + agg[t] * inv[n]
            + r.x * Ws[j] + r.y * Ws[64 + j] + r.z * Ws[128 + j] + r.w * Ws[192 + j];
    h[t] = fmaxf(v, 0.0f);
}

// one wave per edge: lane j scatters feature j
__global__ void scatter_k(const int* __restrict__ src, const int* __restrict__ dst,
                          const float* __restrict__ p, float* __restrict__ agg, int E) {
    int t = blockIdx.x * blockDim.x + threadIdx.x;
    int e = t >> 6;
    if (e >= E) return;
    int j = t & 63;
    unsafeAtomicAdd(&agg[dst[e] * 64 + j], p[src[e] * 64 + j]);
}

// ---------------------------------------------------------------------------
// Tiled GEMM: C[M x P] = act(A[M x 64] @ W[64 x P] [+ b] [+ agg*inv])
// block = 256 threads, computes a 64(row) x 64(col) tile; 4x4 per thread.
// ---------------------------------------------------------------------------
template <bool RELU, bool AGG, bool HASB>
__global__ __launch_bounds__(256, 4)
void gemm_k(const float* __restrict__ A, const float* __restrict__ W,
            const float* __restrict__ b, const float* __restrict__ agg,
            const float* __restrict__ inv, float* __restrict__ C,
            int M, int P) {
    __shared__ __align__(16) float hT[64][68];   // A tile, transposed (pad 68: b128-aligned, read-conflict-free)
    __shared__ __align__(16) float wt[64][64];   // W tile
    const int t = threadIdx.x;
    const int m0 = blockIdx.x * 64;
    const int c0 = blockIdx.y * 64;

#pragma unroll
    for (int it = 0; it < 16; ++it) {
        int m = it * 4 + (t >> 6);
        int k = t & 63;
        int row = m0 + m;
        hT[k][m] = (row < M) ? A[(size_t)row * 64 + k] : 0.f;
    }
#pragma unroll
    for (int it = 0; it < 16; ++it) {
        int k = it * 4 + (t >> 6);
        int c = t & 63;
        wt[k][c] = W[(size_t)k * P + c0 + c];
    }
    __syncthreads();

    const int cr = (t & 15) << 2;          // 0..60
    const int rr = (t >> 4) << 2;          // 0..60
    float acc[4][4] = {};
#pragma unroll 8
    for (int k = 0; k < 64; ++k) {
        float4 a = *(const float4*)&hT[k][rr];
        float4 w = *(const float4*)&wt[k][cr];
        acc[0][0] = fmaf(a.x, w.x, acc[0][0]); acc[0][1] = fmaf(a.x, w.y, acc[0][1]);
        acc[0][2] = fmaf(a.x, w.z, acc[0][2]); acc[0][3] = fmaf(a.x, w.w, acc[0][3]);
        acc[1][0] = fmaf(a.y, w.x, acc[1][0]); acc[1][1] = fmaf(a.y, w.y, acc[1][1]);
        acc[1][2] = fmaf(a.y, w.z, acc[1][2]); acc[1][3] = fmaf(a.y, w.w, acc[1][3]);
        acc[2][0] = fmaf(a.z, w.x, acc[2][0]); acc[2][1] = fmaf(a.z, w.y, acc[2][1]);
        acc[2][2] = fmaf(a.z, w.z, acc[2][2]); acc[2][3] = fmaf(a.z, w.w, acc[2][3]);
        acc[3][0] = fmaf(a.w, w.x, acc[3][0]); acc[3][1] = fmaf(a.w, w.y, acc[3][1]);
        acc[3][2] = fmaf(a.w, w.z, acc[3][2]); acc[3][3] = fmaf(a.w, w.w, acc[3][3]);
    }

#pragma unroll
    for (int i = 0; i < 4; ++i) {
        int row = m0 + rr + i;
        if (row >= M) continue;
        size_t off = (size_t)row * P + c0 + cr;
        float4 r;
        r.x = acc[i][0]; r.y = acc[i][1]; r.z = acc[i][2]; r.w = acc[i][3];
        if (HASB) {
            r.x += b[c0 + cr]; r.y += b[c0 + cr + 1];
            r.z += b[c0 + cr + 2]; r.w += b[c0 + cr + 3];
        }
        if (AGG) {  // only used with P==64; agg is M x 64, same layout as C
            float iv = inv[row];
            r.x = fmaf(agg[off], iv, r.x);     r.y = fmaf(agg[off + 1], iv, r.y);
            r.z = fmaf(agg[off + 2], iv, r.z); r.w = fmaf(agg[off + 3], iv, r.w);
        }
        if (RELU) {
            r.x = fmaxf(r.x, 0.f); r.y = fmaxf(r.y, 0.f);
            r.z = fmaxf(r.z, 0.f); r.w = fmaxf(r.w, 0.f);
        }
        *(float4*)&C[off] = r;
    }
}

// Wbig[k][c], 64x256: c<64: We1[k][c] ; <128: Wl1[k][c-64] ; <192: We1[64+k][c-128] ; else Wl1[64+k][c-192]
__global__ void pack_k(const float* __restrict__ We1, const float* __restrict__ Wl1,
                       float* __restrict__ Wbig) {
    int t = blockIdx.x * 256 + threadIdx.x;
    if (t >= 64 * 256) return;
    int k = t >> 8, c = t & 255;
    float v;
    if (c < 64)       v = We1[k * 64 + c];
    else if (c < 128) v = Wl1[k * 64 + (c - 64)];
    else if (c < 192) v = We1[(64 + k) * 64 + (c - 128)];
    else              v = Wl1[(64 + k) * 64 + (c - 192)];
    Wbig[t] = v;
}

// ---------------------------------------------------------------------------
// Edge scorer: persistent waves, one wave per edge per iteration.
// ST[n][0:64]=hn@We1(top), [64:128]=hn@Wl1(top), [128:192]=hn@We1(mid), [192:256]=hn@Wl1(mid)
// ---------------------------------------------------------------------------
__global__ __launch_bounds__(256, 8)
void edge_k(const int* __restrict__ src, const int* __restrict__ dst,
            const float* __restrict__ ef, const float* __restrict__ ST,
            const float* __restrict__ We1, const float* __restrict__ be1,
            const float* __restrict__ We2, const float* __restrict__ be2,
            const float* __restrict__ Wl1, const float* __restrict__ bl1,
            const float* __restrict__ Wl2, const float* __restrict__ bl2,
            float* __restrict__ out, int E, int nwaves) {
    const int j = threadIdx.x & 63;
    const int wid = __builtin_amdgcn_readfirstlane(
        blockIdx.x * (blockDim.x >> 6) + (threadIdx.x >> 6));
    // per-lane constant weights -> registers, loaded once
    float wet[5], wlt[5];
#pragma unroll
    for (int k = 0; k < 5; ++k) {
        wet[k] = We1[(128 + k) * 64 + j];
        wlt[k] = Wl1[(128 + k) * 64 + j];
    }
    const float vbe1 = be1[j], vwe2 = We2[j], vbl1 = bl1[j], vwl2 = Wl2[j];
    const float vbe2 = be2[0], vbl2 = bl2[0];

    for (int e = wid; e < E; e += nwaves) {
        int s = src[e], d = dst[e];
        const float* ps = ST + (size_t)s * 256;
        const float* pd = ST + (size_t)d * 256;
        float t1 = ps[j] + pd[128 + j] + vbe1;
        float u  = ps[64 + j] + pd[192 + j];
#pragma unroll
        for (int k = 0; k < 5; ++k) {
            float ek = ef[e * 5 + k];      // e uniform -> scalar loads
            t1 = fmaf(ek, wet[k], t1);
            u  = fmaf(ek, wlt[k], u);
        }
        float z = fast_tanh(t1) * vwe2;
#pragma unroll
        for (int m = 32; m > 0; m >>= 1) z += __shfl_xor(z, m);
        float w = fast_sigmoid(z + vbe2);
        float o = fmaxf(fmaf(w, u, vbl1), 0.f) * vwl2;
#pragma unroll
        for (int m = 32; m > 0; m >>= 1) o += __shfl_xor(o, m);
        if (j == 0) out[e] = o + vbl2;
    }
}

extern "C" void kernel_launch(void* const* d_in, const int* in_sizes, int n_in,
                              void* d_out, int out_size, void* d_ws, size_t ws_size,
                              hipStream_t stream) {
    const float* nf  = (const float*)d_in[0];
    const float* ef  = (const float*)d_in[1];
    const int*   src = (const int*)d_in[2];
    const int*   dst = (const int*)d_in[3];
    const float* W1s = (const float*)d_in[4];
    const float* W1n = (const float*)d_in[5];
    const float* b1  = (const float*)d_in[6];
    const float* W2s = (const float*)d_in[7];
    const float* W2n = (const float*)d_in[8];
    const float* b2  = (const float*)d_in[9];
    const float* Wnp = (const float*)d_in[10];
    const float* bnp = (const float*)d_in[11];
    const float* We1 = (const float*)d_in[12];
    const float* be1 = (const float*)d_in[13];
    const float* We2 = (const float*)d_in[14];
    const float* be2 = (const float*)d_in[15];
    const float* Wl1 = (const float*)d_in[16];
    const float* bl1 = (const float*)d_in[17];
    const float* Wl2 = (const float*)d_in[18];
    const float* bl2 = (const float*)d_in[19];

    const int N = in_sizes[0] / 4;
    const int E = in_sizes[2];

    // ws layout (floats), total 321N (same budget as round 1, proven to fit):
    //  inv: [0, N)              (reused for Wbig after gemm-h2)
    //  G:   [N, 65N)            agg1, agg2, then hn
    //  X:   [65N, 129N)         p1, p2, then h2   -- start of ST region
    //  Z:   [129N, 193N)        h1
    //  ST:  [65N, 321N)         written only after X/Z are dead
    float* wsf  = (float*)d_ws;
    float* inv  = wsf;
    float* Wbig = wsf;                        // overlays inv (dead by pack time)
    float* G    = wsf + N;
    float* X    = G + (size_t)64 * N;
    float* Z    = X + (size_t)64 * N;
    float* ST   = X;                          // 256N, overlays X..Z..T
    float* out  = (float*)d_out;

    const int NT = N * 64;
    const int nblkN  = (NT + 255) / 256;
    const int nblkE  = (E + 255) / 256;
    const int nblkEw = (int)(((long long)E * 64 + 255) / 256);
    const int gemmx  = (N + 63) / 64;
    const int EDGE_BLOCKS = 2048;
    const int nwaves = EDGE_BLOCKS * 4;

    // degree -> inv_deg
    zero_k<<<(N + 255) / 256, 256, 0, stream>>>(inv, N);
    count_deg<<<nblkE, 256, 0, stream>>>(dst, inv, E);
    inv_deg_k<<<(N + 255) / 256, 256, 0, stream>>>(inv, N);

    // layer 1
    proj1_k<<<nblkN, 256, 0, stream>>>(nf, W1n, X, N);                  // p1 -> X
    zero_k<<<nblkN, 256, 0, stream>>>(G, NT);
    scatter_k<<<nblkEw, 256, 0, stream>>>(src, dst, X, G, E);           // agg1 -> G
    sage1_fin<<<nblkN, 256, 0, stream>>>(nf, W1s, b1, G, inv, Z, N);    // h1 -> Z

    // layer 2
    gemm_k<false, false, false><<<dim3(gemmx, 1), 256, 0, stream>>>(
        Z, W2n, nullptr, nullptr, nullptr, X, N, 64);                   // p2 -> X
    zero_k<<<nblkN, 256, 0, stream>>>(G, NT);
    scatter_k<<<nblkEw, 256, 0, stream>>>(src, dst, X, G, E);           // agg2 -> G
    gemm_k<true, true, true><<<dim3(gemmx, 1), 256, 0, stream>>>(
        Z, W2s, b2, G, inv, X, N, 64);                                  // h2 -> X

    // per-node MLP, then ST table
    gemm_k<true, false, true><<<dim3(gemmx, 1), 256, 0, stream>>>(
        X, Wnp, bnp, nullptr, nullptr, G, N, 64);                       // hn -> G
    pack_k<<<64, 256, 0, stream>>>(We1, Wl1, Wbig);                     // Wbig -> inv slot
    gemm_k<false, false, false><<<dim3(gemmx, 4), 256, 0, stream>>>(
        G, Wbig, nullptr, nullptr, nullptr, ST, N, 256);                // ST

    // per-edge scoring
    edge_k<<<EDGE_BLOCKS, 256, 0, stream>>>(src, dst, ef, ST,
                                            We1, be1, We2, be2, Wl1, bl1, Wl2, bl2,
                                            out, E, nwaves);
}

// Round 3
// 912.616 us; speedup vs baseline: 1.8053x; 1.4773x over previous
//
#include <hip/hip_runtime.h>
#include <math.h>

// ---------------------------------------------------------------------------
// EdgeClassifier: 2x SAGEConv(mean) -> per-node MLP -> edge scorer
//  * per-node algebra: relu(h[src]@W+b) == relu(h@W+b)[src]
//  * ef@W splits into per-node ST table (N x 256) + tiny edge_feat tail
//  * aggregation: device-built CSR + one-wave-per-node GATHER (no f32 scatter
//    atomics -- round2 showed 400MB write-through per scatter)
//  * hn fused into the ST gemm (never materialized) to fit ws budget
// ---------------------------------------------------------------------------

__device__ __forceinline__ float fast_tanh(float x) {
    x = fminf(fmaxf(x, -15.f), 15.f);
    float e2 = __expf(2.f * x);
    return (e2 - 1.f) * __builtin_amdgcn_rcpf(e2 + 1.f);
}
__device__ __forceinline__ float fast_sigmoid(float x) {
    x = fminf(fmaxf(x, -60.f), 60.f);
    return __builtin_amdgcn_rcpf(1.f + __expf(-x));
}

__global__ void zero_int_k(int* __restrict__ p, int n) {
    int i = blockIdx.x * blockDim.x + threadIdx.x;
    if (i < n) p[i] = 0;
}

__global__ void count_deg_k(const int* __restrict__ dst, int* __restrict__ deg, int E) {
    int i = blockIdx.x * blockDim.x + threadIdx.x;
    if (i < E) atomicAdd(&deg[dst[i]], 1);
}

// block-level exclusive scan; block totals to bsum
__global__ void scan1_k(const int* __restrict__ deg, int* __restrict__ off,
                        int* __restrict__ bsum, int N) {
    __shared__ int tmp[256];
    int i = blockIdx.x * 256 + threadIdx.x;
    int v = (i < N) ? deg[i] : 0;
    tmp[threadIdx.x] = v;
    __syncthreads();
#pragma unroll
    for (int s = 1; s < 256; s <<= 1) {
        int t = (threadIdx.x >= s) ? tmp[threadIdx.x - s] : 0;
        __syncthreads();
        tmp[threadIdx.x] += t;
        __syncthreads();
    }
    if (i < N) off[i] = tmp[threadIdx.x] - v;   // exclusive within block
    if (threadIdx.x == 255) bsum[blockIdx.x] = tmp[255];
}

// single-block exclusive scan of block sums (nb <= 512)
__global__ void scan2_k(int* __restrict__ bsum, int nb) {
    __shared__ int tmp[512];
    int i = threadIdx.x;
    int v = (i < nb) ? bsum[i] : 0;
    tmp[i] = v;
    __syncthreads();
#pragma unroll
    for (int s = 1; s < 512; s <<= 1) {
        int t = (i >= s) ? tmp[i - s] : 0;
        __syncthreads();
        tmp[i] += t;
        __syncthreads();
    }
    if (i < nb) bsum[i] = tmp[i] - v;           // exclusive
}

// add block offsets; init cursor = off; write off[N] = E
__global__ void scan3_k(int* __restrict__ off, const int* __restrict__ bsum,
                        int* __restrict__ cur, int N, int E) {
    int i = blockIdx.x * 256 + threadIdx.x;
    if (i < N) {
        int v = off[i] + bsum[blockIdx.x];
        off[i] = v;
        cur[i] = v;
    }
    if (i == 0) off[N] = E;
}

__global__ void fill_csr_k(const int* __restrict__ src, const int* __restrict__ dst,
                           int* __restrict__ cur, int* __restrict__ csr, int E) {
    int e = blockIdx.x * blockDim.x + threadIdx.x;
    if (e >= E) return;
    int pos = atomicAdd(&cur[dst[e]], 1);
    csr[pos] = src[e];
}

// p[n][j] = sum_{k<4} nf[n][k] * W[k][j]
__global__ void proj1_k(const float* __restrict__ nf, const float* __restrict__ W,
                        float* __restrict__ p, int N) {
    int t = blockIdx.x * blockDim.x + threadIdx.x;
    if (t >= N * 64) return;
    int n = t >> 6, j = t & 63;
    float4 r = ((const float4*)nf)[n];
    p[t] = r.x * W[j] + r.y * W[64 + j] + r.z * W[128 + j] + r.w * W[192 + j];
}

// one wave per node: h1[n][j] = relu(nf@W1s + mean_agg(p1) + b1)
__global__ __launch_bounds__(256, 8)
void gather1_k(const int* __restrict__ off, const int* __restrict__ csr,
               const float* __restrict__ p, const float* __restrict__ nf,
               const float* __restrict__ W1s, const float* __restrict__ b1,
               float* __restrict__ h1, int N) {
    int n = blockIdx.x * 4 + (threadIdx.x >> 6);
    if (n >= N) return;
    int j = threadIdx.x & 63;
    int s0 = off[n], s1 = off[n + 1];
    float acc = 0.f;
    int i = s0;
    for (; i + 4 <= s1; i += 4) {
        int a = csr[i], b = csr[i + 1], c = csr[i + 2], d = csr[i + 3];
        acc += p[(size_t)a * 64 + j] + p[(size_t)b * 64 + j]
             + p[(size_t)c * 64 + j] + p[(size_t)d * 64 + j];
    }
    for (; i < s1; ++i) acc += p[(size_t)csr[i] * 64 + j];
    float invd = 1.f / fmaxf((float)(s1 - s0), 1.f);
    float4 r = ((const float4*)nf)[n];
    float v = b1[j] + acc * invd
            + r.x * W1s[j] + r.y * W1s[64 + j] + r.z * W1s[128 + j] + r.w * W1s[192 + j];
    h1[(size_t)n * 64 + j] = fmaxf(v, 0.f);
}

// one wave per node: agg[n][j] = mean of p2 over in-neighbors (pre-scaled)
__global__ __launch_bounds__(256, 8)
void gather2_k(const int* __restrict__ off, const int* __restrict__ csr,
               const float* __restrict__ p, float* __restrict__ agg, int N) {
    int n = blockIdx.x * 4 + (threadIdx.x >> 6);
    if (n >= N) return;
    int j = threadIdx.x & 63;
    int s0 = off[n], s1 = off[n + 1];
    float acc = 0.f;
    int i = s0;
    for (; i + 4 <= s1; i += 4) {
        int a = csr[i], b = csr[i + 1], c = csr[i + 2], d = csr[i + 3];
        acc += p[(size_t)a * 64 + j] + p[(size_t)b * 64 + j]
             + p[(size_t)c * 64 + j] + p[(size_t)d * 64 + j];
    }
    for (; i < s1; ++i) acc += p[(size_t)csr[i] * 64 + j];
    float invd = 1.f / fmaxf((float)(s1 - s0), 1.f);
    agg[(size_t)n * 64 + j] = acc * invd;
}

// ---------------------------------------------------------------------------
// Tiled GEMM: C[M x 64] = act(A[M x 64] @ W[64 x 64] [+ b] [+ agg])
// block = 256 threads, 64x64 tile, 4x4 per thread. agg is pre-scaled.
// ---------------------------------------------------------------------------
template <bool RELU, bool AGG, bool HASB>
__global__ __launch_bounds__(256, 4)
void gemm_k(const float* __restrict__ A, const float* __restrict__ W,
            const float* __restrict__ b, const float* __restrict__ agg,
            float* __restrict__ C, int M) {
    __shared__ __align__(16) float hT[64][68];
    __shared__ __align__(16) float wt[64][64];
    const int t = threadIdx.x;
    const int m0 = blockIdx.x * 64;
#pragma unroll
    for (int it = 0; it < 16; ++it) {
        int m = it * 4 + (t >> 6);
        int k = t & 63;
        int row = m0 + m;
        hT[k][m] = (row < M) ? A[(size_t)row * 64 + k] : 0.f;
    }
#pragma unroll
    for (int it = 0; it < 16; ++it) {
        int k = it * 4 + (t >> 6);
        int c = t & 63;
        wt[k][c] = W[(size_t)k * 64 + c];
    }
    __syncthreads();
    const int cr = (t & 15) << 2;
    const int rr = (t >> 4) << 2;
    float acc[4][4] = {};
#pragma unroll 8
    for (int k = 0; k < 64; ++k) {
        float4 a = *(const float4*)&hT[k][rr];
        float4 w = *(const float4*)&wt[k][cr];
        acc[0][0] = fmaf(a.x, w.x, acc[0][0]); acc[0][1] = fmaf(a.x, w.y, acc[0][1]);
        acc[0][2] = fmaf(a.x, w.z, acc[0][2]); acc[0][3] = fmaf(a.x, w.w, acc[0][3]);
        acc[1][0] = fmaf(a.y, w.x, acc[1][0]); acc[1][1] = fmaf(a.y, w.y, acc[1][1]);
        acc[1][2] = fmaf(a.y, w.z, acc[1][2]); acc[1][3] = fmaf(a.y, w.w, acc[1][3]);
        acc[2][0] = fmaf(a.z, w.x, acc[2][0]); acc[2][1] = fmaf(a.z, w.y, acc[2][1]);
        acc[2][2] = fmaf(a.z, w.z, acc[2][2]); acc[2][3] = fmaf(a.z, w.w, acc[2][3]);
        acc[3][0] = fmaf(a.w, w.x, acc[3][0]); acc[3][1] = fmaf(a.w, w.y, acc[3][1]);
        acc[3][2] = fmaf(a.w, w.z, acc[3][2]); acc[3][3] = fmaf(a.w, w.w, acc[3][3]);
    }
#pragma unroll
    for (int i = 0; i < 4; ++i) {
        int row = m0 + rr + i;
        if (row >= M) continue;
        size_t o = (size_t)row * 64 + cr;
        float4 r = {acc[i][0], acc[i][1], acc[i][2], acc[i][3]};
        if (HASB) { r.x += b[cr]; r.y += b[cr + 1]; r.z += b[cr + 2]; r.w += b[cr + 3]; }
        if (AGG)  { r.x += agg[o]; r.y += agg[o + 1]; r.z += agg[o + 2]; r.w += agg[o + 3]; }
        if (RELU) { r.x = fmaxf(r.x, 0.f); r.y = fmaxf(r.y, 0.f);
                    r.z = fmaxf(r.z, 0.f); r.w = fmaxf(r.w, 0.f); }
        *(float4*)&C[o] = r;
    }
}

// Wbig[k][c], 64x256: c<64: We1[k][c]; <128: Wl1[k][c-64]; <192: We1[64+k][c-128]; else Wl1[64+k][c-192]
__global__ void pack_k(const float* __restrict__ We1, const float* __restrict__ Wl1,
                       float* __restrict__ Wbig) {
    int t = blockIdx.x * 256 + threadIdx.x;
    if (t >= 64 * 256) return;
    int k = t >> 8, c = t & 255;
    float v;
    if (c < 64)       v = We1[k * 64 + c];
    else if (c < 128) v = Wl1[k * 64 + (c - 64)];
    else if (c < 192) v = We1[(64 + k) * 64 + (c - 128)];
    else              v = Wl1[(64 + k) * 64 + (c - 192)];
    Wbig[t] = v;
}

// ---------------------------------------------------------------------------
// Fused: hn = relu(h2 @ Wnp + bnp) (stage 1, kept in LDS), ST-cols = hn @ Wbig
// grid: (ceil(N/64), 4); blockIdx.y picks 64 of Wbig's 256 cols.
// ---------------------------------------------------------------------------
__global__ __launch_bounds__(256, 4)
void stgemm_k(const float* __restrict__ h2, const float* __restrict__ Wnp,
              const float* __restrict__ bnp, const float* __restrict__ Wbig,
              float* __restrict__ ST, int N) {
    __shared__ __align__(16) float hT[64][68];   // h2^T, then hn^T
    __shared__ __align__(16) float wt[64][64];
    const int t = threadIdx.x;
    const int m0 = blockIdx.x * 64;
    const int c0 = blockIdx.y * 64;
#pragma unroll
    for (int it = 0; it < 16; ++it) {
        int m = it * 4 + (t >> 6);
        int k = t & 63;
        int row = m0 + m;
        hT[k][m] = (row < N) ? h2[(size_t)row * 64 + k] : 0.f;
    }
#pragma unroll
    for (int it = 0; it < 16; ++it) {
        int k = it * 4 + (t >> 6);
        int c = t & 63;
        wt[k][c] = Wnp[k * 64 + c];
    }
    __syncthreads();
    const int cr = (t & 15) << 2;
    const int rr = (t >> 4) << 2;
    float acc[4][4] = {};
#pragma unroll 8
    for (int k = 0; k < 64; ++k) {
        float4 a = *(const float4*)&hT[k][rr];
        float4 w = *(const float4*)&wt[k][cr];
        acc[0][0] = fmaf(a.x, w.x, acc[0][0]); acc[0][1] = fmaf(a.x, w.y, acc[0][1]);
        acc[0][2] = fmaf(a.x, w.z, acc[0][2]); acc[0][3] = fmaf(a.x, w.w, acc[0][3]);
        acc[1][0] = fmaf(a.y, w.x, acc[1][0]); acc[1][1] = fmaf(a.y, w.y, acc[1][1]);
        acc[1][2] = fmaf(a.y, w.z, acc[1][2]); acc[1][3] = fmaf(a.y, w.w, acc[1][3]);
        acc[2][0] = fmaf(a.z, w.x, acc[2][0]); acc[2][1] = fmaf(a.z, w.y, acc[2][1]);
        acc[2][2] = fmaf(a.z, w.z, acc[2][2]); acc[2][3] = fmaf(a.z, w.w, acc[2][3]);
        acc[3][0] = fmaf(a.w, w.x, acc[3][0]); acc[3][1] = fmaf(a.w, w.y, acc[3][1]);
        acc[3][2] = fmaf(a.w, w.z, acc[3][2]); acc[3][3] = fmaf(a.w, w.w, acc[3][3]);
    }
    __syncthreads();   // everyone done reading hT
    // hn^T[col][row] = relu(acc + bnp[col])
#pragma unroll
    for (int i = 0; i < 4; ++i)
#pragma unroll
        for (int q = 0; q < 4; ++q)
            hT[cr + q][rr + i] = fmaxf(acc[i][q] + bnp[cr + q], 0.f);
    // stage-2 weights
#pragma unroll
    for (int it = 0; it < 16; ++it) {
        int k = it * 4 + (t >> 6);
        int c = t & 63;
        wt[k][c] = Wbig[(size_t)k * 256 + c0 + c];
    }
    __syncthreads();
    float ac2[4][4] = {};
#pragma unroll 8
    for (int k = 0; k < 64; ++k) {
        float4 a = *(const float4*)&hT[k][rr];
        float4 w = *(const float4*)&wt[k][cr];
        ac2[0][0] = fmaf(a.x, w.x, ac2[0][0]); ac2[0][1] = fmaf(a.x, w.y, ac2[0][1]);
        ac2[0][2] = fmaf(a.x, w.z, ac2[0][2]); ac2[0][3] = fmaf(a.x, w.w, ac2[0][3]);
        ac2[1][0] = fmaf(a.y, w.x, ac2[1][0]); ac2[1][1] = fmaf(a.y, w.y, ac2[1][1]);
        ac2[1][2] = fmaf(a.y, w.z, ac2[1][2]); ac2[1][3] = fmaf(a.y, w.w, ac2[1][3]);
        ac2[2][0] = fmaf(a.z, w.x, ac2[2][0]); ac2[2][1] = fmaf(a.z, w.y, ac2[2][1]);
        ac2[2][2] = fmaf(a.z, w.z, ac2[2][2]); ac2[2][3] = fmaf(a.z, w.w, ac2[2][3]);
        ac2[3][0] = fmaf(a.w, w.x, ac2[3][0]); ac2[3][1] = fmaf(a.w, w.y, ac2[3][1]);
        ac2[3][2] = fmaf(a.w, w.z, ac2[3][2]); ac2[3][3] = fmaf(a.w, w.w, ac2[3][3]);
    }
#pragma unroll
    for (int i = 0; i < 4; ++i) {
        int row = m0 + rr + i;
        if (row >= N) continue;
        float4 r = {ac2[i][0], ac2[i][1], ac2[i][2], ac2[i][3]};
        *(float4*)&ST[(size_t)row * 256 + c0 + cr] = r;
    }
}

// ---------------------------------------------------------------------------
// Edge scorer: persistent waves, weights in registers.
// ---------------------------------------------------------------------------
__global__ __launch_bounds__(256, 8)
void edge_k(const int* __restrict__ src, const int* __restrict__ dst,
            const float* __restrict__ ef, const float* __restrict__ ST,
            const float* __restrict__ We1, const float* __restrict__ be1,
            const float* __restrict__ We2, const float* __restrict__ be2,
            const float* __restrict__ Wl1, const float* __restrict__ bl1,
            const float* __restrict__ Wl2, const float* __restrict__ bl2,
            float* __restrict__ out, int E, int nwaves) {
    const int j = threadIdx.x & 63;
    const int wid = __builtin_amdgcn_readfirstlane(
        blockIdx.x * (blockDim.x >> 6) + (threadIdx.x >> 6));
    float wet[5], wlt[5];
#pragma unroll
    for (int k = 0; k < 5; ++k) {
        wet[k] = We1[(128 + k) * 64 + j];
        wlt[k] = Wl1[(128 + k) * 64 + j];
    }
    const float vbe1 = be1[j], vwe2 = We2[j], vbl1 = bl1[j], vwl2 = Wl2[j];
    const float vbe2 = be2[0], vbl2 = bl2[0];

    for (int e = wid; e < E; e += nwaves) {
        int s = src[e], d = dst[e];
        const float* ps = ST + (size_t)s * 256;
        const float* pd = ST + (size_t)d * 256;
        float t1 = ps[j] + pd[128 + j] + vbe1;
        float u  = ps[64 + j] + pd[192 + j];
#pragma unroll
        for (int k = 0; k < 5; ++k) {
            float ek = ef[e * 5 + k];
            t1 = fmaf(ek, wet[k], t1);
            u  = fmaf(ek, wlt[k], u);
        }
        float z = fast_tanh(t1) * vwe2;
#pragma unroll
        for (int m = 32; m > 0; m >>= 1) z += __shfl_xor(z, m);
        float w = fast_sigmoid(z + vbe2);
        float o = fmaxf(fmaf(w, u, vbl1), 0.f) * vwl2;
#pragma unroll
        for (int m = 32; m > 0; m >>= 1) o += __shfl_xor(o, m);
        if (j == 0) out[e] = o + vbl2;
    }
}

extern "C" void kernel_launch(void* const* d_in, const int* in_sizes, int n_in,
                              void* d_out, int out_size, void* d_ws, size_t ws_size,
                              hipStream_t stream) {
    const float* nf  = (const float*)d_in[0];
    const float* ef  = (const float*)d_in[1];
    const int*   src = (const int*)d_in[2];
    const int*   dst = (const int*)d_in[3];
    const float* W1s = (const float*)d_in[4];
    const float* W1n = (const float*)d_in[5];
    const float* b1  = (const float*)d_in[6];
    const float* W2s = (const float*)d_in[7];
    const float* W2n = (const float*)d_in[8];
    const float* b2  = (const float*)d_in[9];
    const float* Wnp = (const float*)d_in[10];
    const float* bnp = (const float*)d_in[11];
    const float* We1 = (const float*)d_in[12];
    const float* be1 = (const float*)d_in[13];
    const float* We2 = (const float*)d_in[14];
    const float* be2 = (const float*)d_in[15];
    const float* Wl1 = (const float*)d_in[16];
    const float* bl1 = (const float*)d_in[17];
    const float* Wl2 = (const float*)d_in[18];
    const float* bl2 = (const float*)d_in[19];

    const int N = in_sizes[0] / 4;
    const int E = in_sizes[2];

    // ws layout (floats unless noted), peak ~128.07 MB (round-1 proven 128.4):
    //  ST:  [0, 256N)                      written LAST (stgemm), read by edge_k
    //    S1: [0, 64N)       p1, then p2    (dead before stgemm)
    //    S2: [64N, 128N)    h1             (dead before stgemm)
    //    S3: [128N, 192N)   agg2           (dead before stgemm)
    //    ints overlay [192N, ...): deg(N), off(N+1), cur(N), csr(E), bsum(512)
    //                                      (all dead before stgemm)
    //  H2:  [256N, 320N)                   read by stgemm (outside ST)
    //  Wbig:[320N, 320N+16384)
    float* wsf = (float*)d_ws;
    float* ST  = wsf;
    float* S1  = wsf;
    float* S2  = wsf + (size_t)64 * N;
    float* S3  = wsf + (size_t)128 * N;
    int*   ip  = (int*)(wsf + (size_t)192 * N);
    int* deg   = ip;
    int* off   = ip + N;
    int* cur   = ip + 2 * (size_t)N + 1;
    int* csr   = ip + 3 * (size_t)N + 1;
    int* bsum  = csr + E;
    float* H2   = wsf + (size_t)256 * N;
    float* Wbig = wsf + (size_t)320 * N;
    float* out  = (float*)d_out;

    const int nblkN1 = (N + 255) / 256;            // 391
    const int nblkE  = (E + 255) / 256;
    const int nblkNT = (N * 64 + 255) / 256;
    const int nblkNw = (N + 3) / 4;                // gather: 4 waves/block
    const int gemmx  = (N + 63) / 64;
    const int EDGE_BLOCKS = 2048;
    const int nwaves = EDGE_BLOCKS * 4;

    // CSR build
    zero_int_k<<<nblkN1, 256, 0, stream>>>(deg, N);
    count_deg_k<<<nblkE, 256, 0, stream>>>(dst, deg, E);
    scan1_k<<<nblkN1, 256, 0, stream>>>(deg, off, bsum, N);
    scan2_k<<<1, 512, 0, stream>>>(bsum, nblkN1);
    scan3_k<<<nblkN1, 256, 0, stream>>>(off, bsum, cur, N, E);
    fill_csr_k<<<nblkE, 256, 0, stream>>>(src, dst, cur, csr, E);

    // layer 1: project, gather-aggregate + fused self/bias/relu
    proj1_k<<<nblkNT, 256, 0, stream>>>(nf, W1n, S1, N);                 // p1 -> S1
    gather1_k<<<nblkNw, 256, 0, stream>>>(off, csr, S1, nf, W1s, b1, S2, N); // h1 -> S2

    // layer 2
    gemm_k<false, false, false><<<gemmx, 256, 0, stream>>>(S2, W2n, nullptr, nullptr, S1, N); // p2 -> S1
    gather2_k<<<nblkNw, 256, 0, stream>>>(off, csr, S1, S3, N);          // agg2 -> S3
    gemm_k<true, true, true><<<gemmx, 256, 0, stream>>>(S2, W2s, b2, S3, H2, N); // h2 -> H2

    // fused per-node MLP + ST table
    pack_k<<<64, 256, 0, stream>>>(We1, Wl1, Wbig);
    stgemm_k<<<dim3(gemmx, 4), 256, 0, stream>>>(H2, Wnp, bnp, Wbig, ST, N);

    // per-edge scoring
    edge_k<<<EDGE_BLOCKS, 256, 0, stream>>>(src, dst, ef, ST,
                                            We1, be1, We2, be2, Wl1, bl1, Wl2, bl2,
                                            out, E, nwaves);
}

// Round 4
// 777.045 us; speedup vs baseline: 2.1203x; 1.1745x over previous
//
#include <hip/hip_runtime.h>
#include <math.h>

// ---------------------------------------------------------------------------
// EdgeClassifier: 2x SAGEConv(mean) -> per-node MLP -> edge scorer
//  * layer-1 agg: mean commutes with projection -> aggregate raw nf (4-dim)
//  * layer-2 agg: CSR gather, float4 x 4-rows-per-load
//  * ST table: bf16, (We1,Wl1) column-interleaved -> 1 uint load/edge
//  * edge_k: CSR (dst-bucket) order -> dst half loaded once per node
// ---------------------------------------------------------------------------

__device__ __forceinline__ float fast_tanh(float x) {
    x = fminf(fmaxf(x, -15.f), 15.f);
    float e2 = __expf(2.f * x);
    return (e2 - 1.f) * __builtin_amdgcn_rcpf(e2 + 1.f);
}
__device__ __forceinline__ float fast_sigmoid(float x) {
    x = fminf(fmaxf(x, -60.f), 60.f);
    return __builtin_amdgcn_rcpf(1.f + __expf(-x));
}
__device__ __forceinline__ unsigned short f2bf(float f) {   // RNE
    unsigned u = __float_as_uint(f);
    u = u + 0x7FFFu + ((u >> 16) & 1u);
    return (unsigned short)(u >> 16);
}

__global__ void zero_int_k(int* __restrict__ p, int n) {
    int i = blockIdx.x * blockDim.x + threadIdx.x;
    if (i < n) p[i] = 0;
}

__global__ void count_deg_k(const int* __restrict__ dst, int* __restrict__ deg, int E) {
    int i = blockIdx.x * blockDim.x + threadIdx.x;
    if (i < E) atomicAdd(&deg[dst[i]], 1);
}

__global__ void scan1_k(const int* __restrict__ deg, int* __restrict__ off,
                        int* __restrict__ bsum, int N) {
    __shared__ int tmp[256];
    int i = blockIdx.x * 256 + threadIdx.x;
    int v = (i < N) ? deg[i] : 0;
    tmp[threadIdx.x] = v;
    __syncthreads();
#pragma unroll
    for (int s = 1; s < 256; s <<= 1) {
        int t = (threadIdx.x >= s) ? tmp[threadIdx.x - s] : 0;
        __syncthreads();
        tmp[threadIdx.x] += t;
        __syncthreads();
    }
    if (i < N) off[i] = tmp[threadIdx.x] - v;
    if (threadIdx.x == 255) bsum[blockIdx.x] = tmp[255];
}

__global__ void scan2_k(int* __restrict__ bsum, int nb) {
    __shared__ int tmp[512];
    int i = threadIdx.x;
    int v = (i < nb) ? bsum[i] : 0;
    tmp[i] = v;
    __syncthreads();
#pragma unroll
    for (int s = 1; s < 512; s <<= 1) {
        int t = (i >= s) ? tmp[i - s] : 0;
        __syncthreads();
        tmp[i] += t;
        __syncthreads();
    }
    if (i < nb) bsum[i] = tmp[i] - v;
}

__global__ void scan3_k(int* __restrict__ off, const int* __restrict__ bsum,
                        int* __restrict__ cur, int N, int E) {
    int i = blockIdx.x * 256 + threadIdx.x;
    if (i < N) {
        int v = off[i] + bsum[blockIdx.x];
        off[i] = v;
        cur[i] = v;
    }
    if (i == 0) off[N] = E;
}

__global__ void fill_csr_k(const int* __restrict__ src, const int* __restrict__ dst,
                           int* __restrict__ cur, int* __restrict__ csr_src,
                           int* __restrict__ csr_eid, int E) {
    int e = blockIdx.x * blockDim.x + threadIdx.x;
    if (e >= E) return;
    int pos = atomicAdd(&cur[dst[e]], 1);
    csr_src[pos] = src[e];
    csr_eid[pos] = e;
}

// thread per node: agg_nf[n] = mean of nf[csr_src] (4-dim)
__global__ void aggnf_k(const int* __restrict__ off, const int* __restrict__ csr_src,
                        const float* __restrict__ nf, float* __restrict__ agg, int N) {
    int n = blockIdx.x * blockDim.x + threadIdx.x;
    if (n >= N) return;
    int s0 = off[n], s1 = off[n + 1];
    float4 a = {0.f, 0.f, 0.f, 0.f};
    int i = s0;
    for (; i + 4 <= s1; i += 4) {
        float4 r0 = ((const float4*)nf)[csr_src[i]];
        float4 r1 = ((const float4*)nf)[csr_src[i + 1]];
        float4 r2 = ((const float4*)nf)[csr_src[i + 2]];
        float4 r3 = ((const float4*)nf)[csr_src[i + 3]];
        a.x += r0.x + r1.x + r2.x + r3.x;
        a.y += r0.y + r1.y + r2.y + r3.y;
        a.z += r0.z + r1.z + r2.z + r3.z;
        a.w += r0.w + r1.w + r2.w + r3.w;
    }
    for (; i < s1; ++i) {
        float4 r = ((const float4*)nf)[csr_src[i]];
        a.x += r.x; a.y += r.y; a.z += r.z; a.w += r.w;
    }
    float invd = 1.f / fmaxf((float)(s1 - s0), 1.f);
    a.x *= invd; a.y *= invd; a.z *= invd; a.w *= invd;
    ((float4*)agg)[n] = a;
}

// h1[n][j] = relu(nf@W1s + agg_nf@W1n + b1)
__global__ void h1_k(const float* __restrict__ nf, const float* __restrict__ agg,
                     const float* __restrict__ W1s, const float* __restrict__ W1n,
                     const float* __restrict__ b1, float* __restrict__ h1, int N) {
    int t = blockIdx.x * blockDim.x + threadIdx.x;
    if (t >= N * 64) return;
    int n = t >> 6, j = t & 63;
    float4 r = ((const float4*)nf)[n];
    float4 a = ((const float4*)agg)[n];
    float v = b1[j]
            + r.x * W1s[j] + r.y * W1s[64 + j] + r.z * W1s[128 + j] + r.w * W1s[192 + j]
            + a.x * W1n[j] + a.y * W1n[64 + j] + a.z * W1n[128 + j] + a.w * W1n[192 + j];
    h1[t] = fmaxf(v, 0.f);
}

// one wave per node: aggh1[n] = mean of h1[csr_src] rows.
// lane l: group g=l>>4 handles row csr_src[i+g], features 4*(l&15)..+3
__global__ __launch_bounds__(256, 8)
void gatherh1_k(const int* __restrict__ off, const int* __restrict__ csr_src,
                const float* __restrict__ h1, float* __restrict__ aggh1, int N) {
    int n = blockIdx.x * 4 + (threadIdx.x >> 6);
    if (n >= N) return;
    int l = threadIdx.x & 63;
    int g = l >> 4, fb = (l & 15) << 2;
    int s0 = off[n], s1 = off[n + 1];
    float4 acc = {0.f, 0.f, 0.f, 0.f};
    int i = s0;
    for (; i + 4 <= s1; i += 4) {
        int row = csr_src[i + g];
        float4 v = *(const float4*)&h1[(size_t)row * 64 + fb];
        acc.x += v.x; acc.y += v.y; acc.z += v.z; acc.w += v.w;
    }
    int rem = s1 - i;
    if (g < rem) {
        int row = csr_src[i + g];
        float4 v = *(const float4*)&h1[(size_t)row * 64 + fb];
        acc.x += v.x; acc.y += v.y; acc.z += v.z; acc.w += v.w;
    }
#pragma unroll
    for (int m = 16; m <= 32; m <<= 1) {
        acc.x += __shfl_xor(acc.x, m);
        acc.y += __shfl_xor(acc.y, m);
        acc.z += __shfl_xor(acc.z, m);
        acc.w += __shfl_xor(acc.w, m);
    }
    if (l < 16) {
        float invd = 1.f / fmaxf((float)(s1 - s0), 1.f);
        acc.x *= invd; acc.y *= invd; acc.z *= invd; acc.w *= invd;
        *(float4*)&aggh1[(size_t)n * 64 + fb] = acc;
    }
}

// h2 = relu(h1@W2s + aggh1@W2n + b2); two-phase LDS reuse
__global__ __launch_bounds__(256, 4)
void gemm2_k(const float* __restrict__ A1, const float* __restrict__ A2,
             const float* __restrict__ W1, const float* __restrict__ W2,
             const float* __restrict__ b, float* __restrict__ C, int M) {
    __shared__ __align__(16) float hT[64][68];
    __shared__ __align__(16) float wt[64][64];
    const int t = threadIdx.x;
    const int m0 = blockIdx.x * 64;
    const int cr = (t & 15) << 2, rr = (t >> 4) << 2;
    float acc[4][4] = {};
    for (int ph = 0; ph < 2; ++ph) {
        const float* A = ph ? A2 : A1;
        const float* W = ph ? W2 : W1;
        if (ph) __syncthreads();
#pragma unroll
        for (int it = 0; it < 16; ++it) {
            int m = it * 4 + (t >> 6), k = t & 63, row = m0 + m;
            hT[k][m] = (row < M) ? A[(size_t)row * 64 + k] : 0.f;
        }
#pragma unroll
        for (int it = 0; it < 16; ++it) {
            int k = it * 4 + (t >> 6), c = t & 63;
            wt[k][c] = W[k * 64 + c];
        }
        __syncthreads();
#pragma unroll 8
        for (int k = 0; k < 64; ++k) {
            float4 a = *(const float4*)&hT[k][rr];
            float4 w = *(const float4*)&wt[k][cr];
            acc[0][0] = fmaf(a.x, w.x, acc[0][0]); acc[0][1] = fmaf(a.x, w.y, acc[0][1]);
            acc[0][2] = fmaf(a.x, w.z, acc[0][2]); acc[0][3] = fmaf(a.x, w.w, acc[0][3]);
            acc[1][0] = fmaf(a.y, w.x, acc[1][0]); acc[1][1] = fmaf(a.y, w.y, acc[1][1]);
            acc[1][2] = fmaf(a.y, w.z, acc[1][2]); acc[1][3] = fmaf(a.y, w.w, acc[1][3]);
            acc[2][0] = fmaf(a.z, w.x, acc[2][0]); acc[2][1] = fmaf(a.z, w.y, acc[2][1]);
            acc[2][2] = fmaf(a.z, w.z, acc[2][2]); acc[2][3] = fmaf(a.z, w.w, acc[2][3]);
            acc[3][0] = fmaf(a.w, w.x, acc[3][0]); acc[3][1] = fmaf(a.w, w.y, acc[3][1]);
            acc[3][2] = fmaf(a.w, w.z, acc[3][2]); acc[3][3] = fmaf(a.w, w.w, acc[3][3]);
        }
    }
#pragma unroll
    for (int i = 0; i < 4; ++i) {
        int row = m0 + rr + i;
        if (row >= M) continue;
        float4 r = {acc[i][0] + b[cr], acc[i][1] + b[cr + 1],
                    acc[i][2] + b[cr + 2], acc[i][3] + b[cr + 3]};
        r.x = fmaxf(r.x, 0.f); r.y = fmaxf(r.y, 0.f);
        r.z = fmaxf(r.z, 0.f); r.w = fmaxf(r.w, 0.f);
        *(float4*)&C[(size_t)row * 64 + cr] = r;
    }
}

// Wbig col c: halves [0,128)=src-part, [128,256)=dst-part; within a half,
// col 2j -> We1 col j, col 2j+1 -> Wl1 col j (rows 0..63 src, 64..127 dst)
__global__ void pack_k(const float* __restrict__ We1, const float* __restrict__ Wl1,
                       float* __restrict__ Wbig) {
    int t = blockIdx.x * 256 + threadIdx.x;
    if (t >= 64 * 256) return;
    int k = t >> 8, c = t & 255;
    int half = c >> 7, cc = c & 127;
    int j = cc >> 1, p = cc & 1;
    const float* W = p ? Wl1 : We1;
    Wbig[t] = W[(half * 64 + k) * 64 + j];
}

// hn = relu(h2@Wnp+bnp) in LDS, then ST(bf16) = hn @ Wbig
__global__ __launch_bounds__(256, 4)
void stgemm_k(const float* __restrict__ h2, const float* __restrict__ Wnp,
              const float* __restrict__ bnp, const float* __restrict__ Wbig,
              unsigned short* __restrict__ ST, int N) {
    __shared__ __align__(16) float hT[64][68];
    __shared__ __align__(16) float wt[64][64];
    const int t = threadIdx.x;
    const int m0 = blockIdx.x * 64;
    const int c0 = blockIdx.y * 64;
    const int cr = (t & 15) << 2, rr = (t >> 4) << 2;
#pragma unroll
    for (int it = 0; it < 16; ++it) {
        int m = it * 4 + (t >> 6), k = t & 63, row = m0 + m;
        hT[k][m] = (row < N) ? h2[(size_t)row * 64 + k] : 0.f;
    }
#pragma unroll
    for (int it = 0; it < 16; ++it) {
        int k = it * 4 + (t >> 6), c = t & 63;
        wt[k][c] = Wnp[k * 64 + c];
    }
    __syncthreads();
    float acc[4][4] = {};
#pragma unroll 8
    for (int k = 0; k < 64; ++k) {
        float4 a = *(const float4*)&hT[k][rr];
        float4 w = *(const float4*)&wt[k][cr];
        acc[0][0] = fmaf(a.x, w.x, acc[0][0]); acc[0][1] = fmaf(a.x, w.y, acc[0][1]);
        acc[0][2] = fmaf(a.x, w.z, acc[0][2]); acc[0][3] = fmaf(a.x, w.w, acc[0][3]);
        acc[1][0] = fmaf(a.y, w.x, acc[1][0]); acc[1][1] = fmaf(a.y, w.y, acc[1][1]);
        acc[1][2] = fmaf(a.y, w.z, acc[1][2]); acc[1][3] = fmaf(a.y, w.w, acc[1][3]);
        acc[2][0] = fmaf(a.z, w.x, acc[2][0]); acc[2][1] = fmaf(a.z, w.y, acc[2][1]);
        acc[2][2] = fmaf(a.z, w.z, acc[2][2]); acc[2][3] = fmaf(a.z, w.w, acc[2][3]);
        acc[3][0] = fmaf(a.w, w.x, acc[3][0]); acc[3][1] = fmaf(a.w, w.y, acc[3][1]);
        acc[3][2] = fmaf(a.w, w.z, acc[3][2]); acc[3][3] = fmaf(a.w, w.w, acc[3][3]);
    }
    __syncthreads();
#pragma unroll
    for (int i = 0; i < 4; ++i)
#pragma unroll
        for (int q = 0; q < 4; ++q)
            hT[cr + q][rr + i] = fmaxf(acc[i][q] + bnp[cr + q], 0.f);
#pragma unroll
    for (int it = 0; it < 16; ++it) {
        int k = it * 4 + (t >> 6), c = t & 63;
        wt[k][c] = Wbig[(size_t)k * 256 + c0 + c];
    }
    __syncthreads();
    float ac2[4][4] = {};
#pragma unroll 8
    for (int k = 0; k < 64; ++k) {
        float4 a = *(const float4*)&hT[k][rr];
        float4 w = *(const float4*)&wt[k][cr];
        ac2[0][0] = fmaf(a.x, w.x, ac2[0][0]); ac2[0][1] = fmaf(a.x, w.y, ac2[0][1]);
        ac2[0][2] = fmaf(a.x, w.z, ac2[0][2]); ac2[0][3] = fmaf(a.x, w.w, ac2[0][3]);
        ac2[1][0] = fmaf(a.y, w.x, ac2[1][0]); ac2[1][1] = fmaf(a.y, w.y, ac2[1][1]);
        ac2[1][2] = fmaf(a.y, w.z, ac2[1][2]); ac2[1][3] = fmaf(a.y, w.w, ac2[1][3]);
        ac2[2][0] = fmaf(a.z, w.x, ac2[2][0]); ac2[2][1] = fmaf(a.z, w.y, ac2[2][1]);
        ac2[2][2] = fmaf(a.z, w.z, ac2[2][2]); ac2[2][3] = fmaf(a.z, w.w, ac2[2][3]);
        ac2[3][0] = fmaf(a.w, w.x, ac2[3][0]); ac2[3][1] = fmaf(a.w, w.y, ac2[3][1]);
        ac2[3][2] = fmaf(a.w, w.z, ac2[3][2]); ac2[3][3] = fmaf(a.w, w.w, ac2[3][3]);
    }
#pragma unroll
    for (int i = 0; i < 4; ++i) {
        int row = m0 + rr + i;
        if (row >= N) continue;
        ushort4 pk;
        pk.x = f2bf(ac2[i][0]); pk.y = f2bf(ac2[i][1]);
        pk.z = f2bf(ac2[i][2]); pk.w = f2bf(ac2[i][3]);
        *(ushort4*)&ST[(size_t)row * 256 + c0 + cr] = pk;
    }
}

// ---------------------------------------------------------------------------
// Edge scorer: persistent waves, CSR (dst-bucket) order.
// ST32[n*128 + c]: c<64 -> src-part pair (lo=We1, hi=Wl1), c>=64 -> dst-part.
// ---------------------------------------------------------------------------
__global__ __launch_bounds__(256, 8)
void edge_k(const int* __restrict__ off, const int* __restrict__ csr_src,
            const int* __restrict__ csr_eid, const float* __restrict__ ef,
            const unsigned int* __restrict__ ST32,
            const float* __restrict__ We1, const float* __restrict__ be1,
            const float* __restrict__ We2, const float* __restrict__ be2,
            const float* __restrict__ Wl1, const float* __restrict__ bl1,
            const float* __restrict__ Wl2, const float* __restrict__ bl2,
            float* __restrict__ out, int N, int nwaves) {
    const int j = threadIdx.x & 63;
    const int wid = __builtin_amdgcn_readfirstlane(
        blockIdx.x * (blockDim.x >> 6) + (threadIdx.x >> 6));
    float wet[5], wlt[5];
#pragma unroll
    for (int k = 0; k < 5; ++k) {
        wet[k] = We1[(128 + k) * 64 + j];
        wlt[k] = Wl1[(128 + k) * 64 + j];
    }
    const float vbe1 = be1[j], vwe2 = We2[j], vbl1 = bl1[j], vwl2 = Wl2[j];
    const float vbe2 = be2[0], vbl2 = bl2[0];

    for (int n = wid; n < N; n += nwaves) {
        int s0 = off[n], s1 = off[n + 1];
        if (s0 >= s1) continue;
        unsigned pw = ST32[(size_t)n * 128 + 64 + j];
        float tbase = __uint_as_float(pw << 16) + vbe1;          // We1 dst part + be1
        float ubase = __uint_as_float(pw & 0xFFFF0000u);         // Wl1 dst part
        for (int i = s0; i < s1; ++i) {
            int s = csr_src[i];
            int eid = csr_eid[i];
            unsigned sw = ST32[(size_t)s * 128 + j];
            float t1 = __uint_as_float(sw << 16) + tbase;
            float u  = __uint_as_float(sw & 0xFFFF0000u) + ubase;
            const float* ep = ef + (size_t)eid * 5;
#pragma unroll
            for (int k = 0; k < 5; ++k) {
                float ek = ep[k];
                t1 = fmaf(ek, wet[k], t1);
                u  = fmaf(ek, wlt[k], u);
            }
            float z = fast_tanh(t1) * vwe2;
#pragma unroll
            for (int m = 32; m > 0; m >>= 1) z += __shfl_xor(z, m);
            float w = fast_sigmoid(z + vbe2);
            float o = fmaxf(fmaf(w, u, vbl1), 0.f) * vwl2;
#pragma unroll
            for (int m = 32; m > 0; m >>= 1) o += __shfl_xor(o, m);
            if (j == 0) out[eid] = o + vbl2;
        }
    }
}

extern "C" void kernel_launch(void* const* d_in, const int* in_sizes, int n_in,
                              void* d_out, int out_size, void* d_ws, size_t ws_size,
                              hipStream_t stream) {
    const float* nf  = (const float*)d_in[0];
    const float* ef  = (const float*)d_in[1];
    const int*   src = (const int*)d_in[2];
    const int*   dst = (const int*)d_in[3];
    const float* W1s = (const float*)d_in[4];
    const float* W1n = (const float*)d_in[5];
    const float* b1  = (const float*)d_in[6];
    const float* W2s = (const float*)d_in[7];
    const float* W2n = (const float*)d_in[8];
    const float* b2  = (const float*)d_in[9];
    const float* Wnp = (const float*)d_in[10];
    const float* bnp = (const float*)d_in[11];
    const float* We1 = (const float*)d_in[12];
    const float* be1 = (const float*)d_in[13];
    const float* We2 = (const float*)d_in[14];
    const float* be2 = (const float*)d_in[15];
    const float* Wl1 = (const float*)d_in[16];
    const float* bl1 = (const float*)d_in[17];
    const float* Wl2 = (const float*)d_in[18];
    const float* bl2 = (const float*)d_in[19];

    const int N = in_sizes[0] / 4;
    const int E = in_sizes[2];

    // ws layout (float units), peak ~228N (=91.3 MB < proven 128.4 MB):
    //  ST(bf16):  [0, 128N)         written by stgemm, read by edge_k
    //    h1:      [0, 64N)          dead before stgemm
    //    aggh1:   [64N, 128N)       dead before stgemm
    //  h2:        [128N, 192N)      (agg_nf overlays its head early)
    //  ints:      [192N, ~227N): deg N | off N+1 | cur N | csr_src E | csr_eid E | bsum 512
    //  Wbig:      [228N, 228N+16384)
    float* wsf = (float*)d_ws;
    unsigned short* ST = (unsigned short*)wsf;          // 256N bf16
    float* h1    = wsf;                                 // 64N
    float* aggh1 = wsf + (size_t)64 * N;                // 64N
    float* h2    = wsf + (size_t)128 * N;               // 64N
    float* aggnf = h2;                                  // 4N, dead before gemm2 output
    int* ip      = (int*)(wsf + (size_t)192 * N);
    int* deg     = ip;
    int* off     = ip + N;
    int* cur     = ip + 2 * (size_t)N + 1;
    int* csr_src = ip + 3 * (size_t)N + 1;
    int* csr_eid = csr_src + E;
    int* bsum    = csr_eid + E;
    float* Wbig  = wsf + (size_t)228 * N;
    float* out   = (float*)d_out;

    const int nblkN1 = (N + 255) / 256;
    const int nblkE  = (E + 255) / 256;
    const int nblkNT = (N * 64 + 255) / 256;
    const int nblkNw = (N + 3) / 4;
    const int gemmx  = (N + 63) / 64;
    const int EDGE_BLOCKS = 2048;
    const int nwaves = EDGE_BLOCKS * 4;

    // CSR build (with edge ids)
    zero_int_k<<<nblkN1, 256, 0, stream>>>(deg, N);
    count_deg_k<<<nblkE, 256, 0, stream>>>(dst, deg, E);
    scan1_k<<<nblkN1, 256, 0, stream>>>(deg, off, bsum, N);
    scan2_k<<<1, 512, 0, stream>>>(bsum, nblkN1);
    scan3_k<<<nblkN1, 256, 0, stream>>>(off, bsum, cur, N, E);
    fill_csr_k<<<nblkE, 256, 0, stream>>>(src, dst, cur, csr_src, csr_eid, E);

    // layer 1: aggregate raw nf (4-dim), then fused h1
    aggnf_k<<<nblkN1, 256, 0, stream>>>(off, csr_src, nf, aggnf, N);
    h1_k<<<nblkNT, 256, 0, stream>>>(nf, aggnf, W1s, W1n, b1, h1, N);

    // layer 2: gather h1, dual-A gemm
    gatherh1_k<<<nblkNw, 256, 0, stream>>>(off, csr_src, h1, aggh1, N);
    gemm2_k<<<gemmx, 256, 0, stream>>>(h1, aggh1, W2s, W2n, b2, h2, N);

    // fused per-node MLP + bf16 ST table
    pack_k<<<64, 256, 0, stream>>>(We1, Wl1, Wbig);
    stgemm_k<<<dim3(gemmx, 4), 256, 0, stream>>>(h2, Wnp, bnp, Wbig, ST, N);

    // per-edge scoring, CSR order
    edge_k<<<EDGE_BLOCKS, 256, 0, stream>>>(off, csr_src, csr_eid, ef,
                                            (const unsigned int*)ST,
                                            We1, be1, We2, be2, Wl1, bl1, Wl2, bl2,
                                            out, N, nwaves);
}